// Round 1
// baseline (425.164 us; speedup 1.0000x reference)
//
#include <hip/hip_runtime.h>
#include <cstdint>

#define N_EDGES 12288
#define ROWLEN  2432      // 19*128 floats per edge
#define CAP     2048      // per-system bucket capacity (buckets avg 768)

typedef __bf16 bf16;
typedef __bf16 bf16x8 __attribute__((ext_vector_type(8)));
typedef float  f32x4  __attribute__((ext_vector_type(4)));

#define ELEMS0 (640*640)
#define ELEMS1 (1024*1024)
#define ELEMS2 (768*768)

// ws byte offsets
#define WS_IDX_OFF   1024
#define WS_BIAS_OFF  (WS_IDX_OFF + 16*CAP*4)        // 132096
#define WS_W_OFF     (WS_BIAS_OFF + 16*640*4)       // 173056 (16B aligned)

// Branch configs. Note: after the SO(2) "hat" fold, every branch is a square
// GEMM with K == N (hat K = 2*KS for m>=1). XOFF = float offset of the
// branch's coefficient block inside an edge's 2432-float row (same for x and out).
template<int B> struct Cfg;
template<> struct Cfg<0> { static constexpr int K=640,  KS=640, XOFF=0;
                           static constexpr size_t WOFF=0; };
template<> struct Cfg<1> { static constexpr int K=1024, KS=512, XOFF=640;
                           static constexpr size_t WOFF=(size_t)16*ELEMS0; };
template<> struct Cfg<2> { static constexpr int K=768,  KS=384, XOFF=1664;
                           static constexpr size_t WOFF=(size_t)16*ELEMS0+(size_t)16*ELEMS1; };

__device__ __forceinline__ void async_copy16(const void* g, void* l) {
  // global -> LDS direct copy, 16B per lane; LDS dest = base + lane*16.
  auto gp = reinterpret_cast<const __attribute__((address_space(1))) unsigned int*>(
      reinterpret_cast<uintptr_t>(g));
  auto lp = reinterpret_cast<__attribute__((address_space(3))) unsigned int*>(
      (unsigned int)reinterpret_cast<uintptr_t>(l));
  __builtin_amdgcn_global_load_lds(gp, lp, 16, 0, 0);
}

// ---------------- bucketing ----------------
__global__ void bucket_kernel(const int* __restrict__ eb, int* __restrict__ counts,
                              int* __restrict__ idxb) {
  int t = blockIdx.x * 256 + threadIdx.x;
  if (t < N_EDGES) {
    int s = eb[t];
    int p = atomicAdd(counts + s, 1);
    if (p < CAP) idxb[s * CAP + p] = t;
  }
}

// ---------------- mixed bias (b_m0 is zeros, but keep it correct) ----------------
__global__ void bias_kernel(const float* __restrict__ ce, const float* __restrict__ b0,
                            float* __restrict__ bias) {
  int t = blockIdx.x * 256 + threadIdx.x;   // 0..10239
  int s = t / 640, c = t - s * 640;
  float a = 0.f;
#pragma unroll
  for (int e = 0; e < 8; ++e) a += ce[s * 8 + e] * b0[e * 640 + c];
  bias[t] = a;
}

// ---------------- weight mixing + hat fold + swizzle + bf16 cast ----------------
// dst layout per (branch, system): [kblk][ntile][kgrp:4][n:128][k8:8] bf16, so a
// (kblk,ntile) 8KB chunk is contiguous and matches the LDS fragment layout exactly.
template<int B>
__device__ __forceinline__ void mix_body(const float* __restrict__ Wsrc,
                                         const float* ce_s,
                                         unsigned short* __restrict__ Wz, int pos) {
  constexpr int N = Cfg<B>::K, KS = Cfg<B>::KS, NT = N / 128, HALF = N / 2;
  constexpr int SRC_STRIDE = KS * N;            // per-expert source elems
  constexpr size_t DST_STRIDE = (size_t)Cfg<B>::K * N;  // per-system dst elems
  int nn = pos & 127, kgrp = (pos >> 7) & 3, rest = pos >> 9;
  int nt = rest % NT, kblk = rest / NT;
  int i0 = kblk * 32 + kgrp * 8;                // hat row of first of my 8 k's
  int c  = nt * 128 + nn;                       // hat col
  int si = i0, sc = c; float sg = 1.f;
  if (B > 0 && i0 >= KS) {                      // lower half of hat: [-W2 | W1]
    si = i0 - KS;
    if (c < HALF) { sc = c + HALF; sg = -1.f; } else { sc = c - HALF; }
  }
  float w[8][8];
  const float* p0 = Wsrc + (size_t)si * N + sc;
#pragma unroll
  for (int e = 0; e < 8; ++e) {
    const float* p = p0 + (size_t)e * SRC_STRIDE;
#pragma unroll
    for (int j = 0; j < 8; ++j) w[e][j] = sg * p[(size_t)j * N];
  }
  unsigned short* db = Wz + Cfg<B>::WOFF + (size_t)pos * 8;
#pragma unroll
  for (int s = 0; s < 16; ++s) {
    float a[8] = {0, 0, 0, 0, 0, 0, 0, 0};
#pragma unroll
    for (int e = 0; e < 8; ++e) {
      float cc = ce_s[s * 8 + e];
#pragma unroll
      for (int j = 0; j < 8; ++j) a[j] += cc * w[e][j];
    }
    bf16x8 v;
#pragma unroll
    for (int j = 0; j < 8; ++j) v[j] = (bf16)a[j];
    *(bf16x8*)(db + s * DST_STRIDE) = v;
  }
}

__global__ __launch_bounds__(256) void mix_all(const float* __restrict__ W0,
                                               const float* __restrict__ W1,
                                               const float* __restrict__ W2,
                                               const float* __restrict__ ce,
                                               unsigned short* __restrict__ Wz) {
  __shared__ float ce_s[128];
  int tid = threadIdx.x;
  if (tid < 128) ce_s[tid] = ce[tid];
  __syncthreads();
  int bx = blockIdx.x;
  if (bx < 200)      mix_body<0>(W0, ce_s, Wz, bx * 256 + tid);
  else if (bx < 712) mix_body<1>(W1, ce_s, Wz, (bx - 200) * 256 + tid);
  else               mix_body<2>(W2, ce_s, Wz, (bx - 712) * 256 + tid);
}

// ---------------- grouped GEMM (m97 structure) ----------------
template<int B>
__device__ __forceinline__ void gemm_body(const float* __restrict__ x,
                                          const unsigned short* __restrict__ Wz,
                                          const int* __restrict__ counts,
                                          const int* __restrict__ idxb,
                                          const float* __restrict__ bias,
                                          float* __restrict__ out, int ntl,
                                          bf16* lA, bf16* lB, int* eidx) {
  constexpr int K = Cfg<B>::K, NT = K / 128, KB = K / 32, XOFF = Cfg<B>::XOFF;
  constexpr size_t SYS_STRIDE = (size_t)K * K;
  int s = blockIdx.z, mt = blockIdx.y;
  int cnt = counts[s];
  int m0 = mt * 128;
  if (m0 >= cnt) return;
  int tid = threadIdx.x;
  if (tid < 128) {
    int m = m0 + tid;
    eidx[tid] = (m < cnt) ? idxb[s * CAP + m] : -1;
  }
  __syncthreads();
  int wv = tid >> 6, ln = tid & 63;
  int wm = wv >> 1, wn = wv & 1;
  int ar = tid >> 1, ah = tid & 1;   // A staging: row, k-half
  int kq = ln >> 4, lm = ln & 15;
  int myedge = eidx[ar];
  bool av = myedge >= 0;
  const float* ap = x + (size_t)(av ? myedge : 0) * ROWLEN + XOFF + ah * 16;
  const bf16* wb = (const bf16*)Wz + Cfg<B>::WOFF + (size_t)s * SYS_STRIDE + (size_t)ntl * 4096;

  f32x4 acc[4][4];
#pragma unroll
  for (int i = 0; i < 4; ++i)
#pragma unroll
    for (int j = 0; j < 4; ++j) {
      acc[i][j][0] = 0.f; acc[i][j][1] = 0.f; acc[i][j][2] = 0.f; acc[i][j][3] = 0.f;
    }

#pragma unroll 1
  for (int kb = 0; kb < KB; ++kb) {
    // B: async global->LDS, tile already in fragment-swizzled order, 8KB
    const bf16* gB = wb + (size_t)kb * (NT * 4096) + wv * 1024;
    async_copy16(gB + ln * 8, lB + wv * 1024);
    async_copy16(gB + 512 + ln * 8, lB + wv * 1024 + 512);
    // A: fp32 load -> bf16 -> LDS [kgrp][m][k8]
    float4 f0 = {0,0,0,0}, f1 = {0,0,0,0}, f2 = {0,0,0,0}, f3 = {0,0,0,0};
    if (av) {
      const float4* p = (const float4*)(ap + kb * 32);
      f0 = p[0]; f1 = p[1]; f2 = p[2]; f3 = p[3];
    }
    bf16x8 v0, v1;
    v0[0]=(bf16)f0.x; v0[1]=(bf16)f0.y; v0[2]=(bf16)f0.z; v0[3]=(bf16)f0.w;
    v0[4]=(bf16)f1.x; v0[5]=(bf16)f1.y; v0[6]=(bf16)f1.z; v0[7]=(bf16)f1.w;
    v1[0]=(bf16)f2.x; v1[1]=(bf16)f2.y; v1[2]=(bf16)f2.z; v1[3]=(bf16)f2.w;
    v1[4]=(bf16)f3.x; v1[5]=(bf16)f3.y; v1[6]=(bf16)f3.z; v1[7]=(bf16)f3.w;
    *(bf16x8*)&lA[(ah * 2) * 1024 + ar * 8] = v0;
    *(bf16x8*)&lA[(ah * 2 + 1) * 1024 + ar * 8] = v1;
    __syncthreads();
    bf16x8 af[4], bq[4];
#pragma unroll
    for (int mi = 0; mi < 4; ++mi)
      af[mi] = *(const bf16x8*)&lA[kq * 1024 + (wm * 64 + mi * 16 + lm) * 8];
#pragma unroll
    for (int ni = 0; ni < 4; ++ni)
      bq[ni] = *(const bf16x8*)&lB[kq * 1024 + (wn * 64 + ni * 16 + lm) * 8];
#pragma unroll
    for (int mi = 0; mi < 4; ++mi)
#pragma unroll
      for (int ni = 0; ni < 4; ++ni)
        acc[mi][ni] = __builtin_amdgcn_mfma_f32_16x16x32_bf16(af[mi], bq[ni], acc[mi][ni], 0, 0, 0);
    __syncthreads();
  }
  // epilogue: C/D layout col=lane&15, row=(lane>>4)*4+reg
  float bv[4] = {0, 0, 0, 0};
  if (B == 0) {
#pragma unroll
    for (int ni = 0; ni < 4; ++ni)
      bv[ni] = bias[s * 640 + ntl * 128 + wn * 64 + ni * 16 + lm];
  }
#pragma unroll
  for (int mi = 0; mi < 4; ++mi) {
#pragma unroll
    for (int r = 0; r < 4; ++r) {
      int row = wm * 64 + mi * 16 + kq * 4 + r;
      int e = eidx[row];
      if (e < 0) continue;
      float* po = out + (size_t)e * ROWLEN + XOFF + ntl * 128 + wn * 64 + lm;
#pragma unroll
      for (int ni = 0; ni < 4; ++ni) po[ni * 16] = acc[mi][ni][r] + bv[ni];
    }
  }
}

__global__ __launch_bounds__(256) void gemm_all(const float* __restrict__ x,
                                                const unsigned short* __restrict__ Wz,
                                                const int* __restrict__ counts,
                                                const int* __restrict__ idxb,
                                                const float* __restrict__ bias,
                                                float* __restrict__ out) {
  __shared__ bf16 lA[4096];
  __shared__ bf16 lB[4096];
  __shared__ int eidx[128];
  int bx = blockIdx.x;   // 0..18 = (branch, ntile): 5 + 8 + 6
  if (bx < 5)       gemm_body<0>(x, Wz, counts, idxb, bias, out, bx, lA, lB, eidx);
  else if (bx < 13) gemm_body<1>(x, Wz, counts, idxb, bias, out, bx - 5, lA, lB, eidx);
  else              gemm_body<2>(x, Wz, counts, idxb, bias, out, bx - 13, lA, lB, eidx);
}

extern "C" void kernel_launch(void* const* d_in, const int* in_sizes, int n_in,
                              void* d_out, int out_size, void* d_ws, size_t ws_size,
                              hipStream_t stream) {
  const float* x  = (const float*)d_in[0];
  // d_in[1] = x_edge: unused by the reference
  const float* ce = (const float*)d_in[2];
  const int*   eb = (const int*)d_in[3];
  const float* W0 = (const float*)d_in[4];
  const float* b0 = (const float*)d_in[5];
  const float* W1 = (const float*)d_in[6];
  const float* W2 = (const float*)d_in[7];
  float* out = (float*)d_out;
  char* ws = (char*)d_ws;
  int*   counts = (int*)ws;
  int*   idxb   = (int*)(ws + WS_IDX_OFF);
  float* bias   = (float*)(ws + WS_BIAS_OFF);
  unsigned short* Wz = (unsigned short*)(ws + WS_W_OFF);

  hipMemsetAsync(counts, 0, 64, stream);
  bucket_kernel<<<48, 256, 0, stream>>>(eb, counts, idxb);
  bias_kernel<<<40, 256, 0, stream>>>(ce, b0, bias);
  mix_all<<<1000, 256, 0, stream>>>(W0, W1, W2, ce, Wz);
  gemm_all<<<dim3(19, 16, 16), 256, 0, stream>>>(x, Wz, counts, idxb, bias, out);
}